// Round 3
// baseline (906.263 us; speedup 1.0000x reference)
//
#include <hip/hip_runtime.h>
#include <hip/hip_bf16.h>

typedef __bf16 bf16x8 __attribute__((ext_vector_type(8)));
typedef float  f32x4  __attribute__((ext_vector_type(4)));
typedef unsigned short us8 __attribute__((ext_vector_type(8)));

__device__ __forceinline__ unsigned short f2bf(float f) {
    union { float f; unsigned u; } c; c.f = f;
    unsigned u = c.u;
    u += 0x7FFFu + ((u >> 16) & 1u);   // RNE; inputs finite
    return (unsigned short)(u >> 16);
}

// pack 2 floats -> 2 bf16 in one dword (v_cvt_pk_bf16_f32 on gfx950)
__device__ __forceinline__ unsigned pkbf2(float a, float b) {
    __hip_bfloat162 h = __float22bfloat162_rn(make_float2(a, b));
    unsigned r; __builtin_memcpy(&r, &h, 4); return r;
}

// async 16B global -> LDS (dest = wave-uniform base + lane*16)
__device__ __forceinline__ void gl2lds16(const void* g, void* l) {
    __builtin_amdgcn_global_load_lds(
        (const __attribute__((address_space(1))) unsigned int*)g,
        (__attribute__((address_space(3))) unsigned int*)l, 16, 0, 0);
}

#define XS    68        // x ci-stride (ushorts): 136B -> 2-way bank alias (free)
#define NPX   612       // 18 rows x 34 cols halo pixels
#define WST   100       // weight k-stride (ushorts): 200B -> conflict-free for lm reads
#define WHALF 12800     // ushorts per K=96 half-stage (128 co x 100)

// -------- weight pre-transform: OIHW f32 -> [stage=kh*2+half][co][WST] bf16 ----
// Stage s covers kh = s>>1, k in [ (s&1)*96, +96 ), where k = kw*64 + ci.
// Layout is byte-identical to the conv kernel's LDS weight buffer (pure gl2lds copy).
__global__ void __launch_bounds__(256) wxform(const float* __restrict__ W,
                                              unsigned short* __restrict__ wpad) {
    int o = blockIdx.x * 256 + threadIdx.x;          // 6*128*100 = 76800
    if (o < 6 * 128 * WST) {
        int s  = o / WHALF;
        int r  = o % WHALF;
        int co = r / WST;
        int kl = r % WST;
        unsigned short v = 0;
        if (kl < 96) {
            int kg = (s & 1) * 96 + kl;              // k within the kh group
            int kw = kg >> 6;
            int ci = kg & 63;
            v = f2bf(W[co * 576 + ci * 9 + (s >> 1) * 3 + kw]);  // W[co][ci][kh][kw]
        }
        wpad[o] = v;
    }
}

struct Smem {
    unsigned short x[NPX * XS];      // 83232 B : halo [px][ci] bf16
    unsigned short w[2][128 * WST];  // 51200 B : double-buffered K=96 weight halves
    float red[8];
};                                   // 134464 B -> 1 block/CU, 8 waves

// -------- fused conv3x3 + bias + avgpool2 + sigmoid + per-image sum --------
// Block: 512 thr / 8 waves; 16 out rows x 32 cols x 128 co. Wave v owns out
// rows {2v,2v+1} (= one pool row), full 32 cols, all 128 co.
__global__ void __launch_bounds__(512, 2)
conv_fused(const float* __restrict__ x,
           const unsigned short* __restrict__ wpad,
           const float* __restrict__ bias,
           float* __restrict__ out)
{
    __shared__ __align__(16) Smem sm;

    const int tid  = threadIdx.x;
    const int wave = tid >> 6;        // 0..7
    const int lane = tid & 63;
    const int lq   = lane >> 4;
    const int lm   = lane & 15;

    const int ct = blockIdx.x;        // 0..3  col tile (32 wide)
    const int rt = blockIdx.y;        // 0..7  row tile (16 out rows)
    const int n  = blockIdx.z;        // 0..63 image

    const int h0 = rt * 16;
    const int w0 = ct * 32;
    const float* xn = x + (size_t)n * (64u * 128u * 128u);

    // issue weight half-stage 0 early (lands during x staging)
    for (int c = wave; c < 25; c += 8)
        gl2lds16(wpad + c * 512 + lane * 8, &sm.w[0][c * 512]);

    // ---- stage x halo: 64ci x 18h x 34w -> LDS [px][ci] bf16 ----
    for (int it = 0; it < 10; ++it) {
        int t = tid + it * 512;
        if (t < NPX * 8) {                 // 4896 tasks
            int px  = t % NPX;             // consecutive lanes -> consecutive w
            int cig = t / NPX;             // ci-group (8 ci)
            int hh = px / 34, ww = px % 34;
            int h = h0 + hh, w = w0 + ww;
            bool ok = (h < 128) && (w < 128);
            const float* src = xn + (size_t)(cig * 8) * 16384 + h * 128 + w;
            float f[8];
            #pragma unroll
            for (int j = 0; j < 8; ++j) f[j] = ok ? src[j * 16384] : 0.0f;
            union { us8 v; unsigned u[4]; } pk;
            #pragma unroll
            for (int j = 0; j < 4; ++j) pk.u[j] = pkbf2(f[2 * j], f[2 * j + 1]);
            *(us8*)&sm.x[px * XS + cig * 8] = pk.v;
        }
    }

    float bv[8];
    #pragma unroll
    for (int nt = 0; nt < 8; ++nt) bv[nt] = bias[nt * 16 + lm];

    f32x4 acc[4][8];                  // [rl*2+ch][nt]
    #pragma unroll
    for (int m = 0; m < 4; ++m)
        #pragma unroll
        for (int nt = 0; nt < 8; ++nt)
            acc[m][nt] = (f32x4){0.f, 0.f, 0.f, 0.f};

    __syncthreads();                  // x staged + w half 0 landed

    // issue half-stage 1 into buf 1 (drains at the barrier ending stage 0)
    for (int c = wave; c < 25; c += 8)
        gl2lds16(wpad + WHALF + c * 512 + lane * 8, &sm.w[1][c * 512]);

    // ---- main loop: 6 half-stages (kh = s>>1, K=96 each) ----
    for (int s = 0; s < 6; ++s) {
        const int kh   = s >> 1;
        const int koff = (s & 1) * 96;
        const unsigned short* wl = &sm.w[s & 1][0];

        #pragma unroll
        for (int kc = 0; kc < 3; ++kc) {
            const int kg = koff + kc * 32;     // 32-chunk stays inside one kw
            const int kw = kg >> 6;
            const int kq = (kg >> 5) & 1;      // ci half within the tap
            bf16x8 av[4];
            #pragma unroll
            for (int rl = 0; rl < 2; ++rl)
                #pragma unroll
                for (int ch = 0; ch < 2; ++ch) {
                    int px = (2 * wave + rl + kh) * 34 + ch * 16 + lm + kw;
                    av[rl * 2 + ch] = *(const bf16x8*)&sm.x[px * XS + kq * 32 + lq * 8];
                }
            #pragma unroll
            for (int nt = 0; nt < 8; ++nt) {
                bf16x8 b = *(const bf16x8*)&wl[(nt * 16 + lm) * WST + kc * 32 + lq * 8];
                #pragma unroll
                for (int m = 0; m < 4; ++m)
                    acc[m][nt] = __builtin_amdgcn_mfma_f32_16x16x32_bf16(
                        av[m], b, acc[m][nt], 0, 0, 0);
            }
        }

        __syncthreads();   // all waves done with buf (s&1); drains in-flight gl2lds
        if (s < 4) {       // prefetch half-stage s+2 into the buffer just freed
            const unsigned short* src = wpad + (size_t)(s + 2) * WHALF;
            for (int c = wave; c < 25; c += 8)
                gl2lds16(src + c * 512 + lane * 8, &sm.w[s & 1][c * 512]);
        }
    }

    // ---- in-register epilogue: rl pair = vertical pool, rr pairs = horizontal ----
    float part = 0.0f;
    const int ph = rt * 8 + wave;                 // pool row (wave-uniform)
    if (ph < 63) {
        #pragma unroll
        for (int ch = 0; ch < 2; ++ch) {
            const int pwb = ct * 16 + ch * 8 + lq * 2;
            #pragma unroll
            for (int nt = 0; nt < 8; ++nt) {
                f32x4 sv = acc[ch][nt] + acc[2 + ch][nt];   // vertical pool sum
                float p0 = sv[0] + sv[1];
                float p1 = sv[2] + sv[3];
                float bb = bv[nt];
                if (pwb < 63) {
                    float v = 0.25f * p0 + bb;
                    part += 1.0f / (1.0f + __expf(-v));
                }
                if (pwb + 1 < 63) {
                    float v = 0.25f * p1 + bb;
                    part += 1.0f / (1.0f + __expf(-v));
                }
            }
        }
    }

    #pragma unroll
    for (int off = 32; off > 0; off >>= 1)
        part += __shfl_down(part, off, 64);
    if (lane == 0) sm.red[wave] = part;
    __syncthreads();
    if (tid == 0) {
        float t = 0.f;
        #pragma unroll
        for (int i = 0; i < 8; ++i) t += sm.red[i];
        atomicAdd(&out[n], t);
    }
}

extern "C" void kernel_launch(void* const* d_in, const int* in_sizes, int n_in,
                              void* d_out, int out_size, void* d_ws, size_t ws_size,
                              hipStream_t stream) {
    const float* x = (const float*)d_in[0];
    const float* W = (const float*)d_in[1];
    const float* b = (const float*)d_in[2];
    float* out = (float*)d_out;
    unsigned short* wpad = (unsigned short*)d_ws;   // 153600 B used

    hipMemsetAsync(d_out, 0, 64 * sizeof(float), stream);
    wxform<<<300, 256, 0, stream>>>(W, wpad);
    conv_fused<<<dim3(4, 8, 64), 512, 0, stream>>>(x, wpad, b, out);
}

// Round 4
// 655.764 us; speedup vs baseline: 1.3820x; 1.3820x over previous
//
#include <hip/hip_runtime.h>
#include <hip/hip_bf16.h>

typedef __bf16 bf16x8 __attribute__((ext_vector_type(8)));
typedef float  f32x4  __attribute__((ext_vector_type(4)));
typedef unsigned short us8 __attribute__((ext_vector_type(8)));

__device__ __forceinline__ unsigned short f2bf(float f) {
    union { float f; unsigned u; } c; c.f = f;
    unsigned u = c.u;
    u += 0x7FFFu + ((u >> 16) & 1u);   // RNE; inputs finite
    return (unsigned short)(u >> 16);
}
__device__ __forceinline__ unsigned pkbf2(float a, float b) {
    __hip_bfloat162 h = __float22bfloat162_rn(make_float2(a, b));
    unsigned r; __builtin_memcpy(&r, &h, 4); return r;
}
__device__ __forceinline__ void gl2lds16(const void* g, void* l) {
    __builtin_amdgcn_global_load_lds(
        (const __attribute__((address_space(1))) unsigned int*)g,
        (__attribute__((address_space(3))) unsigned int*)l, 16, 0, 0);
}

#define XS   68        // x ci-stride (ushorts): 136B -> 2-way bank alias (free)
#define HPX  252       // 14 rows x 18 cols halo pixels
#define WCH  4096      // ushorts per weight chunk: 128co x 32k (bank-swizzled)
#define EPS  130       // epilogue stride (floats)

// ---- weight pre-transform: OIHW f32 -> 18 chunks [c= tap*2+kc][co][swizzled k32] bf16
// chunk element (co, k=lq*8+j) stored at co*32 + ((lq+co)&3)*8 + j  (16B-frag rotation
// by co: B-read lanes lm (co consecutive) then spread across 8 bank groups -> 2-way max)
__global__ void __launch_bounds__(256) wxform(const float* __restrict__ W,
                                              unsigned short* __restrict__ wsw) {
    int i = blockIdx.x * 256 + threadIdx.x;      // 18*4096 = 73728
    if (i < 18 * WCH) {
        int c   = i >> 12;           // chunk
        int r   = i & 4095;
        int co  = r >> 5;
        int kk  = r & 31;            // k within chunk
        int lq  = kk >> 3;
        int tap = c >> 1;
        int ci  = (c & 1) * 32 + kk;
        float v = W[co * 576 + ci * 9 + tap];    // W[co][ci][kh*3+kw]
        wsw[c * WCH + co * 32 + ((lq + co) & 3) * 8 + (kk & 7)] = f2bf(v);
    }
}

struct Smem {
    union {
        unsigned short x[HPX * XS];  // 34272 B : halo [px][ci] bf16
        float epi[64 * EPS];         // 33280 B : epilogue overlay (after K loop)
    } u;
    unsigned short w[2][WCH];        // 16384 B : double-buffered weight chunks
    float red[4];
};                                   // ~50.7 KB -> 3 blocks/CU

// ---- fused conv3x3 + bias + avgpool2 + sigmoid + per-image sum ----
// Block: 256 thr / 4 waves; tile 12 rows x 16 cols x 128 co. Wave v owns rows
// {3v,3v+1,3v+2} (acc[3][8] = 96 AGPR; launch_bounds(256,3) -> 3 waves/SIMD,
// one wave from each of 3 independent blocks per SIMD).
__global__ void __launch_bounds__(256, 3)
conv_fused(const float* __restrict__ x,
           const unsigned short* __restrict__ wsw,
           const float* __restrict__ bias,
           float* __restrict__ out)
{
    __shared__ __align__(16) Smem sm;

    const int tid  = threadIdx.x;
    const int wave = tid >> 6;
    const int lane = tid & 63;
    const int lq   = lane >> 4;
    const int lm   = lane & 15;
    const int rot  = (lq + lm) & 3;   // weight swizzle rotation (co == lm mod 4)

    const int ct = blockIdx.x;        // 0..7   col tile (16 wide)
    const int rt = blockIdx.y;        // 0..10  row tile (12 tall; last partly masked)
    const int n  = blockIdx.z;        // 0..63  image

    const int h0 = rt * 12;
    const int w0 = ct * 16;
    const float* xn = x + (size_t)n * (64u * 128u * 128u);

    // async prefetch of weight chunk 0 (8 x 1KB, 2 per wave)
    #pragma unroll
    for (int s = 0; s < 2; ++s) {
        int q = wave * 2 + s;
        gl2lds16(wsw + q * 512 + lane * 8, &sm.w[0][q * 512]);
    }

    // ---- stage x halo: 64ci x 14h x 18w -> LDS [px][ci] bf16 ----
    for (int it = 0; it < 8; ++it) {
        int t = tid + it * 256;
        if (t < HPX * 8) {                 // 2016 tasks
            int px  = t % HPX;             // consecutive lanes -> consecutive px
            int cig = t / HPX;             // ci-group (8 ci)
            int hh = px / 18, ww = px % 18;
            int h = h0 + hh, w = w0 + ww;
            bool ok = (h < 128) && (w < 128);
            const float* src = xn + (size_t)(cig * 8) * 16384 + h * 128 + w;
            float f[8];
            #pragma unroll
            for (int j = 0; j < 8; ++j) f[j] = ok ? src[j * 16384] : 0.0f;
            union { us8 v; unsigned u[4]; } pk;
            #pragma unroll
            for (int j = 0; j < 4; ++j) pk.u[j] = pkbf2(f[2 * j], f[2 * j + 1]);
            *(us8*)&sm.u.x[px * XS + cig * 8] = pk.v;
        }
    }

    f32x4 acc[3][8];                  // [row-tile i][nt] : 96 AGPRs
    #pragma unroll
    for (int i = 0; i < 3; ++i)
        #pragma unroll
        for (int nt = 0; nt < 8; ++nt)
            acc[i][nt] = (f32x4){0.f, 0.f, 0.f, 0.f};

    __syncthreads();                  // x staged + chunk 0 landed

    // ---- K loop: 18 chunks (tap = c>>1, kc = c&1), 1 barrier each ----
    #pragma unroll
    for (int c = 0; c < 18; ++c) {
        if (c + 1 < 18) {             // prefetch next chunk into the freed buffer
            const unsigned short* src = wsw + (c + 1) * WCH;
            #pragma unroll
            for (int s = 0; s < 2; ++s) {
                int q = wave * 2 + s;
                gl2lds16(src + q * 512 + lane * 8, &sm.w[(c + 1) & 1][q * 512]);
            }
        }
        const int tap = c >> 1, kc2 = c & 1;
        const int kh = tap / 3, kw = tap - kh * 3;   // folds: c is unrolled-const

        bf16x8 av[3];
        #pragma unroll
        for (int i = 0; i < 3; ++i) {
            int px = (3 * wave + i + kh) * 18 + lm + kw;
            av[i] = *(const bf16x8*)&sm.u.x[px * XS + kc2 * 32 + lq * 8];
        }
        const unsigned short* wl = &sm.w[c & 1][0];
        #pragma unroll
        for (int nt = 0; nt < 8; ++nt) {
            bf16x8 b = *(const bf16x8*)&wl[(nt * 16 + lm) * 32 + rot * 8];
            #pragma unroll
            for (int i = 0; i < 3; ++i)
                acc[i][nt] = __builtin_amdgcn_mfma_f32_16x16x32_bf16(
                    av[i], b, acc[i][nt], 0, 0, 0);
        }
        __syncthreads();   // frees buf c&1; drains prefetch of c+1
    }

    // ---- epilogue: 3 passes of 4 rows (2 pool rows) via LDS overlay ----
    // D layout: pixel col = lq*4+rr, co = nt*16+lm.
    const float bmy = bias[tid & 127];   // pool-phase co is fixed per thread
    float part = 0.0f;
    #pragma unroll
    for (int p = 0; p < 3; ++p) {
        // write owned row-tiles with rows in [4p, 4p+4)
        #pragma unroll
        for (int i = 0; i < 3; ++i) {
            int r = 3 * wave + i;
            if ((r >> 2) == p) {
                int lr = r & 3;
                #pragma unroll
                for (int nt = 0; nt < 8; ++nt)
                    #pragma unroll
                    for (int rr = 0; rr < 4; ++rr)
                        sm.u.epi[(lr * 16 + lq * 4 + rr) * EPS + nt * 16 + lm]
                            = acc[i][nt][rr];
            }
        }
        __syncthreads();
        // pool 2x2 + bias + sigmoid: 2048 cells (2 pr x 8 pc x 128 co)
        #pragma unroll
        for (int it = 0; it < 8; ++it) {
            int cell = tid + it * 256;
            int co  = cell & 127;          // == tid & 127
            int idx = cell >> 7;
            int pc  = idx & 7;
            int prl = idx >> 3;            // 0..1
            int pr = rt * 6 + p * 2 + prl;
            int pw = ct * 8 + pc;
            if (pr < 63 && pw < 63) {
                int r2 = 2 * prl, c2 = 2 * pc;
                float s = sm.u.epi[((r2    ) * 16 + c2    ) * EPS + co]
                        + sm.u.epi[((r2    ) * 16 + c2 + 1) * EPS + co]
                        + sm.u.epi[((r2 + 1) * 16 + c2    ) * EPS + co]
                        + sm.u.epi[((r2 + 1) * 16 + c2 + 1) * EPS + co];
                float v = 0.25f * s + bmy;
                part += 1.0f / (1.0f + __expf(-v));
            }
        }
        __syncthreads();
    }

    // ---- block reduce -> one atomicAdd per block ----
    #pragma unroll
    for (int off = 32; off > 0; off >>= 1)
        part += __shfl_down(part, off, 64);
    if (lane == 0) sm.red[wave] = part;
    __syncthreads();
    if (tid == 0)
        atomicAdd(&out[n], sm.red[0] + sm.red[1] + sm.red[2] + sm.red[3]);
}

extern "C" void kernel_launch(void* const* d_in, const int* in_sizes, int n_in,
                              void* d_out, int out_size, void* d_ws, size_t ws_size,
                              hipStream_t stream) {
    const float* x = (const float*)d_in[0];
    const float* W = (const float*)d_in[1];
    const float* b = (const float*)d_in[2];
    float* out = (float*)d_out;
    unsigned short* wsw = (unsigned short*)d_ws;   // 147456 B used

    hipMemsetAsync(d_out, 0, 64 * sizeof(float), stream);
    wxform<<<288, 256, 0, stream>>>(W, wsw);
    conv_fused<<<dim3(8, 11, 64), 256, 0, stream>>>(x, wsw, b, out);
}

// Round 5
// 586.912 us; speedup vs baseline: 1.5441x; 1.1173x over previous
//
#include <hip/hip_runtime.h>

typedef int   v8i  __attribute__((ext_vector_type(8)));
typedef float v16f __attribute__((ext_vector_type(16)));

// async 16B global -> LDS (dest = wave-uniform base + lane*16)
__device__ __forceinline__ void gl2lds16(const void* g, void* l) {
    __builtin_amdgcn_global_load_lds(
        (const __attribute__((address_space(1))) unsigned int*)g,
        (__attribute__((address_space(3))) unsigned int*)l, 16, 0, 0);
}

#define XROWB 72            // bytes per px row in LDS (64 fp8 + 8 pad; 18 dwords -> 2-way banks)
#define HPX   340           // 10 rows x 34 cols halo pixels
#define XBUFB (HPX * XROWB) // 24480 B per x buffer
#define WROWB 72            // bytes per co row (64 fp8 + 8 pad)
#define WKHB  (3 * 128 * WROWB)  // 27648 B: 3 taps (one kh) of weights
#define SCALE1 0x7F7F7F7F   // E8M0 = 127 -> 1.0 in every byte

// ---- weight pre-transform: OIHW f32 -> fp8 [tap][co][72B row] ----
__global__ void __launch_bounds__(128) wxform(const float* __restrict__ W,
                                              unsigned char* __restrict__ wf8) {
    int r = blockIdx.x * 128 + threadIdx.x;      // 1152 = 9 taps * 128 co
    if (r < 1152) {
        int tap = r / 128, co = r % 128;
        unsigned char* dst = wf8 + r * WROWB;
        #pragma unroll 4
        for (int p = 0; p < 32; ++p) {           // ci pairs
            float f0 = W[co * 576 + (2 * p    ) * 9 + tap];
            float f1 = W[co * 576 + (2 * p + 1) * 9 + tap];
            unsigned d = __builtin_amdgcn_cvt_pk_fp8_f32(f0, f1, 0, false);
            dst[2 * p]     = (unsigned char)(d & 0xFF);
            dst[2 * p + 1] = (unsigned char)((d >> 8) & 0xFF);
        }
    }
}

struct __align__(16) Smem {
    unsigned char xb[2][XBUFB];   // 48960 B : double-buffered x halo [px][ci] fp8
    unsigned char wb[WKHB];       // 27648 B : 3 taps (current kh) [kw][co][ci] fp8
    float red[4];
};                                // 76624 B -> 2 blocks/CU

// stage a range of x-halo tasks for row-tile at h0 into xb (fp8)
__device__ __forceinline__ void stage_x(const float* __restrict__ xn, int h0, int w0,
                                        unsigned char* __restrict__ xb,
                                        int q0, int q1, int tid) {
    for (int q = q0 + tid; q < q1; q += 256) {   // q in [0, 2720): 340 px * 8 ci-groups
        int px  = q % HPX;
        int cig = q / HPX;
        int hh = px / 34, ww = px % 34;
        int h = h0 + hh, w = w0 + ww;
        bool ok = (h < 128) && (w < 128);
        const float* src = xn + (size_t)(cig * 8) * 16384 + h * 128 + w;
        float f[8];
        #pragma unroll
        for (int j = 0; j < 8; ++j) f[j] = ok ? src[j * 16384] : 0.0f;
        unsigned d0 = __builtin_amdgcn_cvt_pk_fp8_f32(f[0], f[1], 0,  false);
        d0          = __builtin_amdgcn_cvt_pk_fp8_f32(f[2], f[3], d0, true);
        unsigned d1 = __builtin_amdgcn_cvt_pk_fp8_f32(f[4], f[5], 0,  false);
        d1          = __builtin_amdgcn_cvt_pk_fp8_f32(f[6], f[7], d1, true);
        unsigned long long v = ((unsigned long long)d1 << 32) | d0;
        *(unsigned long long*)(xb + px * XROWB + cig * 8) = v;
    }
}

// ---- fused conv3x3 + bias + avgpool2 + sigmoid + per-image sum (MX-fp8) ----
// Block: 256 thr / 4 waves; tile 8 rows x 32 w x 128 co; wave v owns rows {2v,2v+1}.
// MFMA 32x32x64 f8f6f4, scales=1.0. m = (w_local<<1)|h_local so each 2x2 pool
// cell = 4 consecutive acc regs of one lane. 8 row-tiles per block (grid = 512).
__global__ void __launch_bounds__(256, 2)
conv_fused(const float* __restrict__ x,
           const unsigned char* __restrict__ wf8,
           const float* __restrict__ bias,
           float* __restrict__ out)
{
    __shared__ Smem sm;

    const int tid  = threadIdx.x;
    const int wave = tid >> 6;
    const int lane = tid & 63;
    const int lh   = lane >> 5;       // k-half (32 ci)
    const int m    = lane & 31;       // MFMA m/n index

    const int ct  = blockIdx.x;       // 0..3  col tile (32 w)
    const int rtg = blockIdx.y;       // 0..1  row-tile group (8 tiles of 8 rows)
    const int n   = blockIdx.z;       // 0..63 image

    const int w0 = ct * 32;
    const float* xn = x + (size_t)n * (64u * 128u * 128u);

    float bv[4];
    #pragma unroll
    for (int nt = 0; nt < 4; ++nt) bv[nt] = bias[nt * 32 + m];

    const int bh = 2 * wave + (m & 1);   // base halo row (h_local from m bit 0)
    const int bw = m >> 1;               // w_local

    // ---- prologue: weights kh=0 async; x tile 0 into xb[0] ----
    for (int c = wave; c < 27; c += 4)
        gl2lds16(wf8 + c * 1024 + lane * 16, &sm.wb[c * 1024]);
    stage_x(xn, rtg * 64, w0, sm.xb[0], 0, 2720, tid);

    float part = 0.0f;

    for (int t = 0; t < 8; ++t) {
        const int cur = t & 1;
        const int h0n = rtg * 64 + (t + 1) * 8;   // next tile's base row

        v16f acc[2][4];
        #pragma unroll
        for (int mt = 0; mt < 2; ++mt)
            #pragma unroll
            for (int nt = 0; nt < 4; ++nt)
                #pragma unroll
                for (int e = 0; e < 16; ++e) acc[mt][nt][e] = 0.0f;

        for (int kh = 0; kh < 3; ++kh) {
            __syncthreads();   // wb(kh) landed; xb[cur] complete; xb[cur^1] free

            // issue next tile's staging chunk early: drained at the barrier
            // BELOW next kh's gl2lds, covered by this window's MFMAs
            if (t < 7) {
                int q0 = kh * 908;
                int q1 = (kh == 2) ? 2720 : (q0 + 908);
                stage_x(xn, h0n, w0, sm.xb[cur ^ 1], q0, q1, tid);
            }

            #pragma unroll
            for (int kw = 0; kw < 3; ++kw) {
                union { unsigned long long l[4]; v8i v; } a[2], b;
                #pragma unroll
                for (int ch = 0; ch < 2; ++ch) {
                    const unsigned char* ap = &sm.xb[cur][
                        ((bh + kh) * 34 + ch * 16 + bw + kw) * XROWB + lh * 32];
                    #pragma unroll
                    for (int q = 0; q < 4; ++q)
                        a[ch].l[q] = *(const unsigned long long*)(ap + q * 8);
                }
                #pragma unroll
                for (int nt = 0; nt < 4; ++nt) {
                    const unsigned char* bp = &sm.wb[
                        (kw * 128 + nt * 32 + m) * WROWB + lh * 32];
                    #pragma unroll
                    for (int q = 0; q < 4; ++q)
                        b.l[q] = *(const unsigned long long*)(bp + q * 8);
                    acc[0][nt] = __builtin_amdgcn_mfma_scale_f32_32x32x64_f8f6f4(
                        a[0].v, b.v, acc[0][nt], 0, 0, 0, SCALE1, 0, SCALE1);
                    acc[1][nt] = __builtin_amdgcn_mfma_scale_f32_32x32x64_f8f6f4(
                        a[1].v, b.v, acc[1][nt], 0, 0, 0, SCALE1, 0, SCALE1);
                }
            }

            __syncthreads();   // all waves done reading wb(kh)
            if (!(t == 7 && kh == 2)) {
                int nkh = (kh == 2) ? 0 : (kh + 1);
                const unsigned char* src = wf8 + nkh * WKHB;
                for (int c = wave; c < 27; c += 4)
                    gl2lds16(src + c * 1024 + lane * 16, &sm.wb[c * 1024]);
            }
        }

        // ---- in-register epilogue: D row = (reg&3)+8*(reg>>2)+4*lh = (w<<1)|h ----
        const int ph = rtg * 32 + t * 4 + wave;      // pool row (wave-uniform)
        if (ph < 63) {
            #pragma unroll
            for (int mt = 0; mt < 2; ++mt)
                #pragma unroll
                for (int nt = 0; nt < 4; ++nt) {
                    #pragma unroll
                    for (int rg = 0; rg < 4; ++rg) {
                        float s = acc[mt][nt][4 * rg] + acc[mt][nt][4 * rg + 1]
                                + acc[mt][nt][4 * rg + 2] + acc[mt][nt][4 * rg + 3];
                        int pw = ct * 16 + mt * 8 + 2 * rg + lh;
                        if (pw < 63) {
                            float v = 0.25f * s + bv[nt];
                            part += 1.0f / (1.0f + __expf(-v));
                        }
                    }
                }
        }
    }

    // ---- block reduce -> one atomicAdd per block ----
    #pragma unroll
    for (int off = 32; off > 0; off >>= 1)
        part += __shfl_down(part, off, 64);
    if (lane == 0) sm.red[wave] = part;
    __syncthreads();
    if (tid == 0)
        atomicAdd(&out[n], sm.red[0] + sm.red[1] + sm.red[2] + sm.red[3]);
}

extern "C" void kernel_launch(void* const* d_in, const int* in_sizes, int n_in,
                              void* d_out, int out_size, void* d_ws, size_t ws_size,
                              hipStream_t stream) {
    const float* x = (const float*)d_in[0];
    const float* W = (const float*)d_in[1];
    const float* b = (const float*)d_in[2];
    float* out = (float*)d_out;
    unsigned char* wf8 = (unsigned char*)d_ws;    // 82944 B used

    hipMemsetAsync(d_out, 0, 64 * sizeof(float), stream);
    wxform<<<9, 128, 0, stream>>>(W, wf8);
    conv_fused<<<dim3(4, 2, 64), 256, 0, stream>>>(x, wf8, b, out);
}